// Round 1
// baseline (89.086 us; speedup 1.0000x reference)
//
#include <hip/hip_runtime.h>

// Problem constants
#define G_     8
#define D_     144          // C*K*K
#define O_     32
#define CIN_   16
#define HW_    64
#define BATCH_ 8
#define KDIM_  (D_*G_)      // 1152
#define NPIX_  (BATCH_*HW_*HW_)  // 32768

// ws layout: [0,147456) Wt float[1152][32]
//   Wt[k][o] = sum_d W[o][d][k],  k = d*8+g (feature-major, grid-minor)

__global__ void wsum_kernel(const float* __restrict__ W, float* __restrict__ Wt) {
    int t = blockIdx.x * blockDim.x + threadIdx.x;   // 9216 threads, 4 k's each
    if (t >= (KDIM_/4) * O_) return;
    int o  = t / (KDIM_/4);
    int k4 = t % (KDIM_/4);
    const float4* Wp = reinterpret_cast<const float4*>(W + (size_t)o * D_ * KDIM_) + k4;
    float4 s = make_float4(0.f, 0.f, 0.f, 0.f);
    for (int dd = 0; dd < D_; ++dd) {
        float4 v = Wp[dd * (KDIM_/4)];
        s.x += v.x; s.y += v.y; s.z += v.z; s.w += v.w;
    }
    int k = k4 * 4;
    Wt[(size_t)(k+0)*O_ + o] = s.x;
    Wt[(size_t)(k+1)*O_ + o] = s.y;
    Wt[(size_t)(k+2)*O_ + o] = s.z;
    Wt[(size_t)(k+3)*O_ + o] = s.w;
}

// main: k-split x4 across blocks; 256 threads = 256 pixels; 32 acc/thread.
// basis = exp(-((p-g)/denom)^2) = exp2(-(A*(p-g))^2), A = sqrt(log2 e)/denom
__global__ void __launch_bounds__(256, 2)
main_kernel(const float* __restrict__ x, const float* __restrict__ Wt,
            float* __restrict__ out) {
    constexpr int NCHUNK = 4, DPC = D_ / NCHUNK;   // 36 d's per chunk
    constexpr float A_S = 2.1019642153762871f;     // sqrt(log2(e)) * 7/4

    int bx  = blockIdx.x;
    int cid = bx & 3;          // k-chunk
    int pb  = bx >> 2;         // pixel block
    int n   = pb * 256 + threadIdx.x;   // pixel id
    int b   = n >> 12;
    int l   = n & 4095;
    int y   = l >> 6;
    int xw  = l & 63;

    float acc[O_];
#pragma unroll
    for (int o = 0; o < O_; ++o) acc[o] = 0.f;

    const float* xb = x + ((size_t)b * CIN_ << 12);

    for (int dd = 0; dd < DPC; ++dd) {
        int d  = cid * DPC + dd;       // block-uniform -> scalar loads of Wt
        int c  = d / 9;
        int r9 = d - c * 9;
        int kh = r9 / 3;
        int kw = r9 - kh * 3;
        int iy = y + kh - 1, ix = xw + kw - 1;
        float p = 0.f;
        if ((unsigned)iy < 64u && (unsigned)ix < 64u)
            p = xb[(c << 12) + (iy << 6) + ix];

        float e[G_];
#pragma unroll
        for (int g = 0; g < G_; ++g) {
            float gv = -2.0f + (float)g * (4.0f / 7.0f);
            float r  = fmaf(p, A_S, -gv * A_S);    // constant folds
            e[g] = exp2f(-(r * r));
        }

        const float4* w4 = reinterpret_cast<const float4*>(Wt) + (size_t)d * (G_ * O_ / 4);
#pragma unroll
        for (int g = 0; g < G_; ++g) {
            float eg = e[g];
#pragma unroll
            for (int oq = 0; oq < 8; ++oq) {
                float4 w = w4[g * 8 + oq];
                acc[oq*4+0] = fmaf(eg, w.x, acc[oq*4+0]);
                acc[oq*4+1] = fmaf(eg, w.y, acc[oq*4+1]);
                acc[oq*4+2] = fmaf(eg, w.z, acc[oq*4+2]);
                acc[oq*4+3] = fmaf(eg, w.w, acc[oq*4+3]);
            }
        }
    }

    // accumulate partial GEMM result: out[b][o][l]
    float* op = out + ((size_t)b * O_ << 12) + l;
#pragma unroll
    for (int o = 0; o < O_; ++o) {
        unsafeAtomicAdd(op + ((size_t)o << 12), acc[o]);
    }
}

// fused BN stats + normalize: one block per channel o
__global__ void __launch_bounds__(1024)
bn_kernel(float* __restrict__ out, const float* __restrict__ gamma,
          const float* __restrict__ beta) {
    int o   = blockIdx.x;
    int tid = threadIdx.x;
    float4* f4 = reinterpret_cast<float4*>(out);

    float s = 0.f, sq = 0.f;
#pragma unroll
    for (int b = 0; b < BATCH_; ++b) {
        float4 v = f4[(size_t)(b * O_ + o) * 1024 + tid];
        s  += v.x + v.y + v.z + v.w;
        sq += v.x*v.x + v.y*v.y + v.z*v.z + v.w*v.w;
    }

    __shared__ float ls[16], lq[16], bc[2];
    for (int off = 32; off > 0; off >>= 1) {
        s  += __shfl_down(s, off);
        sq += __shfl_down(sq, off);
    }
    int wid = tid >> 6, lane = tid & 63;
    if (lane == 0) { ls[wid] = s; lq[wid] = sq; }
    __syncthreads();
    if (tid == 0) {
        float S = 0.f, Q = 0.f;
        for (int i = 0; i < 16; ++i) { S += ls[i]; Q += lq[i]; }
        float mean = S * (1.f / (float)NPIX_);
        float var  = Q * (1.f / (float)NPIX_) - mean * mean;
        float rstd = rsqrtf(var + 1e-5f);
        float sc   = gamma[o] * rstd;
        bc[0] = sc;
        bc[1] = beta[o] - mean * sc;
    }
    __syncthreads();
    float sc = bc[0], sh = bc[1];
#pragma unroll
    for (int b = 0; b < BATCH_; ++b) {
        size_t idx = (size_t)(b * O_ + o) * 1024 + tid;
        float4 v = f4[idx];
        v.x = v.x * sc + sh;
        v.y = v.y * sc + sh;
        v.z = v.z * sc + sh;
        v.w = v.w * sc + sh;
        f4[idx] = v;
    }
}

extern "C" void kernel_launch(void* const* d_in, const int* in_sizes, int n_in,
                              void* d_out, int out_size, void* d_ws, size_t ws_size,
                              hipStream_t stream) {
    const float* x     = (const float*)d_in[0];
    const float* W     = (const float*)d_in[1];
    const float* gamma = (const float*)d_in[2];
    const float* beta  = (const float*)d_in[3];
    float* out = (float*)d_out;
    float* Wt  = (float*)d_ws;

    hipMemsetAsync(d_out, 0, (size_t)out_size * sizeof(float), stream);
    hipLaunchKernelGGL(wsum_kernel, dim3(36), dim3(256), 0, stream, W, Wt);
    hipLaunchKernelGGL(main_kernel, dim3(512), dim3(256), 0, stream, x, Wt, out);
    hipLaunchKernelGGL(bn_kernel, dim3(O_), dim3(1024), 0, stream, out, gamma, beta);
}

// Round 2
// 48.184 us; speedup vs baseline: 1.8489x; 1.8489x over previous
//
#include <hip/hip_runtime.h>

#define G_     8
#define D_     144
#define O_     32
#define CIN_   16
#define BATCH_ 8
#define KDIM_  (D_*G_)            // 1152
#define NPIX_  (BATCH_*64*64)     // 32768
#define KC_    (KDIM_/32)         // 36 k-chunks of 32

typedef float  f32x4   __attribute__((ext_vector_type(4)));
typedef short  short8v __attribute__((ext_vector_type(8)));

// ws layout:
//   [0, 73728)        Bpack: ushort[36 kc][2 half][64 lane][8 e]  (bf16 B-fragments)
//   [73728, 73984)    sums:  float[64]  (sum[32], sumsq[32])
#define SUMS_OFF 73728

// ---------- Wsum -> bf16 B-fragments ----------
// Wt[k][o] = sum_d W[o][d][k]; emitted directly in mfma B-frag layout:
//   lane = ((k>>3)&3)*16 + (o&15), e = k&7, buf index (kc*2 + o/16)
__global__ void __launch_bounds__(256)
wsum_kernel(const float* __restrict__ W, unsigned short* __restrict__ Bpack) {
    int t = blockIdx.x * 256 + threadIdx.x;       // 36864 = (o,k) pairs
    int o = t / KDIM_;
    int k = t - o * KDIM_;
    const float* p = W + (size_t)o * D_ * KDIM_ + k;
    float s = 0.f;
#pragma unroll 16
    for (int d = 0; d < D_; ++d) s += p[(size_t)d * KDIM_];
    unsigned int u = __float_as_uint(s);
    u += 0x7FFFu + ((u >> 16) & 1u);              // RNE to bf16
    unsigned short hb = (unsigned short)(u >> 16);
    int kc = k >> 5, lane = (((k >> 3) & 3) << 4) | (o & 15);
    int h = o >> 4, e = k & 7;
    Bpack[(((kc * 2 + h) * 64) + lane) * 8 + e] = hb;
}

// pack two f32 -> one u32 of two bf16 (round-half-up), 3 VALU
__device__ __forceinline__ unsigned int pack2bf(float a, float b) {
    unsigned int ua = __float_as_uint(a) + 0x8000u;
    unsigned int ub = __float_as_uint(b) + 0x8000u;
    return __builtin_amdgcn_perm(ub, ua, 0x07060302u);   // {hi16(ub),hi16(ua)}
}

// ---------- fused basis + MFMA GEMM ----------
// block: 4 waves x 16 pixels = 64 pixels; full K (no split); B staged in LDS.
__global__ void main_kernel(const float* __restrict__ x,
                            const unsigned int* __restrict__ Bpack,
                            float* __restrict__ out) {
    constexpr float A_S = 2.1019642153762871f;   // sqrt(log2 e) * 7/4

    __shared__ uint4 Bsh[KC_ * 2 * 64];          // 73728 B

    // stage B fragments (one-time, ~74KB from L2)
    const uint4* Bg = reinterpret_cast<const uint4*>(Bpack);
#pragma unroll
    for (int i = 0; i < 18; ++i) {
        int idx = threadIdx.x + i * 256;
        Bsh[idx] = Bg[idx];
    }
    __syncthreads();

    int tid  = threadIdx.x;
    int l    = tid & 63;
    int wv   = tid >> 6;
    int m    = l & 15;           // pixel within tile
    int hi   = l >> 4;           // k-group -> d offset
    int pixbase = blockIdx.x * 64 + wv * 16;
    int n    = pixbase + m;
    int b    = n >> 12;
    int y    = (n >> 6) & 63;
    int xc   = n & 63;
    const float* xb = x + ((size_t)b << 16);     // b*16*4096

    f32x4 acc0 = {0.f, 0.f, 0.f, 0.f};
    f32x4 acc1 = {0.f, 0.f, 0.f, 0.f};

#pragma unroll 4
    for (int kc = 0; kc < KC_; ++kc) {
        int d  = kc * 4 + hi;
        int c  = (d * 57) >> 9;          // d/9
        int r9 = d - c * 9;
        int kh = (r9 * 11) >> 5;         // r9/3
        int kw = r9 - kh * 3;
        int iy = y + kh - 1;
        int ix = xc + kw - 1;
        bool valid = ((unsigned)iy < 64u) & ((unsigned)ix < 64u);
        float p = valid ? xb[(c << 12) + (iy << 6) + ix] : 0.f;

        float e[G_];
#pragma unroll
        for (int g = 0; g < G_; ++g) {
            float gv = -2.0f + (float)g * (4.0f / 7.0f);
            float r  = fmaf(p, A_S, -gv * A_S);
            e[g] = __builtin_amdgcn_exp2f(-(r * r));
        }
        uint4 au;
        au.x = pack2bf(e[0], e[1]);
        au.y = pack2bf(e[2], e[3]);
        au.z = pack2bf(e[4], e[5]);
        au.w = pack2bf(e[6], e[7]);
        short8v afrag = __builtin_bit_cast(short8v, au);

        short8v b0 = __builtin_bit_cast(short8v, Bsh[(kc * 2 + 0) * 64 + l]);
        short8v b1 = __builtin_bit_cast(short8v, Bsh[(kc * 2 + 1) * 64 + l]);
        acc0 = __builtin_amdgcn_mfma_f32_16x16x32_bf16(afrag, b0, acc0, 0, 0, 0);
        acc1 = __builtin_amdgcn_mfma_f32_16x16x32_bf16(afrag, b1, acc1, 0, 0, 0);
    }

    // D layout: col(o)=lane&15, row(m)=(lane>>4)*4+reg -> 4 consecutive pixels
    int pr = (pixbase & 4095) + hi * 4;
    int o0 = m;                                   // lane&15
    {
        float* dst = out + (((size_t)(b * O_ + o0)) << 12) + pr;
        *reinterpret_cast<f32x4*>(dst) = acc0;
    }
    {
        float* dst = out + (((size_t)(b * O_ + o0 + 16)) << 12) + pr;
        *reinterpret_cast<f32x4*>(dst) = acc1;
    }
}

// ---------- BN stats: one block per (b,o) plane, atomic partials ----------
__global__ void __launch_bounds__(256)
bn_stats(const float* __restrict__ out, float* __restrict__ sums) {
    int pl  = blockIdx.x;                 // 256 planes
    int tid = threadIdx.x;
    const float4* f4 = reinterpret_cast<const float4*>(out) + (size_t)pl * 1024;
    float s = 0.f, q = 0.f;
#pragma unroll
    for (int i = 0; i < 4; ++i) {
        float4 v = f4[tid + i * 256];
        s += v.x + v.y + v.z + v.w;
        q += v.x*v.x + v.y*v.y + v.z*v.z + v.w*v.w;
    }
#pragma unroll
    for (int off = 32; off > 0; off >>= 1) {
        s += __shfl_down(s, off);
        q += __shfl_down(q, off);
    }
    __shared__ float ls[4], lq[4];
    int wid = tid >> 6;
    if ((tid & 63) == 0) { ls[wid] = s; lq[wid] = q; }
    __syncthreads();
    if (tid == 0) {
        float S = ls[0] + ls[1] + ls[2] + ls[3];
        float Q = lq[0] + lq[1] + lq[2] + lq[3];
        int o = pl & 31;
        unsafeAtomicAdd(&sums[o], S);
        unsafeAtomicAdd(&sums[32 + o], Q);
    }
}

// ---------- BN apply ----------
__global__ void __launch_bounds__(256)
bn_apply(float* __restrict__ out, const float* __restrict__ sums,
         const float* __restrict__ gamma, const float* __restrict__ beta) {
    float4* f4 = reinterpret_cast<float4*>(out);
#pragma unroll
    for (int half = 0; half < 2; ++half) {
        int i4 = blockIdx.x * 512 + half * 256 + threadIdx.x;
        int o  = (i4 >> 10) & 31;
        float mean = sums[o] * (1.f / (float)NPIX_);
        float var  = sums[32 + o] * (1.f / (float)NPIX_) - mean * mean;
        float rstd = rsqrtf(var + 1e-5f);
        float sc   = gamma[o] * rstd;
        float sh   = beta[o] - mean * sc;
        float4 v = f4[i4];
        v.x = v.x * sc + sh; v.y = v.y * sc + sh;
        v.z = v.z * sc + sh; v.w = v.w * sc + sh;
        f4[i4] = v;
    }
}

extern "C" void kernel_launch(void* const* d_in, const int* in_sizes, int n_in,
                              void* d_out, int out_size, void* d_ws, size_t ws_size,
                              hipStream_t stream) {
    const float* x     = (const float*)d_in[0];
    const float* W     = (const float*)d_in[1];
    const float* gamma = (const float*)d_in[2];
    const float* beta  = (const float*)d_in[3];
    float* out = (float*)d_out;
    unsigned short* Bpack = (unsigned short*)d_ws;
    float* sums = (float*)((char*)d_ws + SUMS_OFF);

    hipMemsetAsync(sums, 0, 64 * sizeof(float), stream);
    hipLaunchKernelGGL(wsum_kernel, dim3(144), dim3(256), 0, stream, W, Bpack);
    hipLaunchKernelGGL(main_kernel, dim3(512), dim3(256), 0, stream,
                       x, (const unsigned int*)Bpack, out);
    hipLaunchKernelGGL(bn_stats, dim3(256), dim3(256), 0, stream, out, sums);
    hipLaunchKernelGGL(bn_apply, dim3(512), dim3(256), 0, stream,
                       out, sums, gamma, beta);
}

// Round 3
// 31.097 us; speedup vs baseline: 2.8648x; 1.5495x over previous
//
#include <hip/hip_runtime.h>

#define G_     8
#define D_     144
#define O_     32
#define CIN_   16
#define BATCH_ 8
#define KDIM_  (D_*G_)            // 1152
#define NPIX_  (BATCH_*64*64)     // 32768
#define KC_    (KDIM_/32)         // 36 k-chunks of 32

typedef float  f32x4   __attribute__((ext_vector_type(4)));
typedef short  short8v __attribute__((ext_vector_type(8)));

// ws layout:
//   [0, 73728)        Bpack: ushort[36 kc][2 half][64 lane][8 e]  (bf16 B-fragments)
//   [73728, 74752)    part:  float[256]  per-plane sums
//   [74752, 75776)    partq: float[256]  per-plane sumsq
#define PART_OFF  73728
#define PARTQ_OFF 74752

// ---------- Wsum -> bf16 B-fragments ----------
__global__ void __launch_bounds__(256)
wsum_kernel(const float* __restrict__ W, unsigned short* __restrict__ Bpack) {
    int t = blockIdx.x * 256 + threadIdx.x;       // 36864 = (o,k) pairs
    int o = t / KDIM_;
    int k = t - o * KDIM_;
    const float* p = W + (size_t)o * D_ * KDIM_ + k;
    float s = 0.f;
#pragma unroll 16
    for (int d = 0; d < D_; ++d) s += p[(size_t)d * KDIM_];
    unsigned int u = __float_as_uint(s);
    u += 0x7FFFu + ((u >> 16) & 1u);              // RNE to bf16
    unsigned short hb = (unsigned short)(u >> 16);
    int kc = k >> 5, lane = (((k >> 3) & 3) << 4) | (o & 15);
    int h = o >> 4, e = k & 7;
    Bpack[(((kc * 2 + h) * 64) + lane) * 8 + e] = hb;
}

// pack two f32 -> one u32 of two bf16 (round-half-up)
__device__ __forceinline__ unsigned int pack2bf(float a, float b) {
    unsigned int ua = __float_as_uint(a) + 0x8000u;
    unsigned int ub = __float_as_uint(b) + 0x8000u;
    return __builtin_amdgcn_perm(ub, ua, 0x07060302u);   // {hi16(ub),hi16(ua)}
}

// ---------- fused basis + MFMA GEMM ----------
__global__ void main_kernel(const float* __restrict__ x,
                            const unsigned int* __restrict__ Bpack,
                            float* __restrict__ out) {
    constexpr float A_S = 2.1019642153762871f;   // sqrt(log2 e) * 7/4

    __shared__ uint4 Bsh[KC_ * 2 * 64];          // 73728 B

    const uint4* Bg = reinterpret_cast<const uint4*>(Bpack);
#pragma unroll
    for (int i = 0; i < 18; ++i) {
        int idx = threadIdx.x + i * 256;
        Bsh[idx] = Bg[idx];
    }
    __syncthreads();

    int tid  = threadIdx.x;
    int l    = tid & 63;
    int wv   = tid >> 6;
    int m    = l & 15;           // pixel within tile (= output col o base)
    int hi   = l >> 4;           // k-group -> d offset
    int pixbase = blockIdx.x * 64 + wv * 16;
    int n    = pixbase + m;
    int b    = n >> 12;
    int y    = (n >> 6) & 63;
    int xc   = n & 63;
    const float* xb = x + ((size_t)b << 16);

    // ---- phase 1: issue all 36 x-loads (independent, pipelined) ----
    float p[KC_];
#pragma unroll
    for (int kc = 0; kc < KC_; ++kc) {
        int d  = kc * 4 + hi;
        int c  = (d * 57) >> 9;          // d/9
        int r9 = d - c * 9;
        int kh = (r9 * 11) >> 5;         // r9/3
        int kw = r9 - kh * 3;
        int iy = y + kh - 1;
        int ix = xc + kw - 1;
        bool valid = ((unsigned)iy < 64u) & ((unsigned)ix < 64u);
        p[kc] = valid ? xb[(c << 12) + (iy << 6) + ix] : 0.f;
    }

    // ---- phase 2: basis + MFMA ----
    f32x4 acc0 = {0.f, 0.f, 0.f, 0.f};
    f32x4 acc1 = {0.f, 0.f, 0.f, 0.f};

#pragma unroll
    for (int kc = 0; kc < KC_; ++kc) {
        float pv = p[kc];
        float e[G_];
#pragma unroll
        for (int g = 0; g < G_; ++g) {
            float gv = -2.0f + (float)g * (4.0f / 7.0f);
            float r  = fmaf(pv, A_S, -gv * A_S);
            e[g] = __builtin_amdgcn_exp2f(-(r * r));
        }
        uint4 au;
        au.x = pack2bf(e[0], e[1]);
        au.y = pack2bf(e[2], e[3]);
        au.z = pack2bf(e[4], e[5]);
        au.w = pack2bf(e[6], e[7]);
        short8v afrag = __builtin_bit_cast(short8v, au);

        short8v b0 = __builtin_bit_cast(short8v, Bsh[(kc * 2 + 0) * 64 + l]);
        short8v b1 = __builtin_bit_cast(short8v, Bsh[(kc * 2 + 1) * 64 + l]);
        acc0 = __builtin_amdgcn_mfma_f32_16x16x32_bf16(afrag, b0, acc0, 0, 0, 0);
        acc1 = __builtin_amdgcn_mfma_f32_16x16x32_bf16(afrag, b1, acc1, 0, 0, 0);
    }

    // D layout: col(o)=lane&15, row(pixel)=(lane>>4)*4+reg
    int pr = (pixbase & 4095) + hi * 4;
    int o0 = m;
    {
        float* dst = out + (((size_t)(b * O_ + o0)) << 12) + pr;
        *reinterpret_cast<f32x4*>(dst) = acc0;
    }
    {
        float* dst = out + (((size_t)(b * O_ + o0 + 16)) << 12) + pr;
        *reinterpret_cast<f32x4*>(dst) = acc1;
    }
}

// ---------- BN stats: one block per (b,o) plane, NO atomics ----------
__global__ void __launch_bounds__(256)
bn_stats(const float* __restrict__ out, float* __restrict__ part,
         float* __restrict__ partq) {
    int pl  = blockIdx.x;                 // 256 planes, pl = b*32+o
    int tid = threadIdx.x;
    const float4* f4 = reinterpret_cast<const float4*>(out) + (size_t)pl * 1024;
    float s = 0.f, q = 0.f;
#pragma unroll
    for (int i = 0; i < 4; ++i) {
        float4 v = f4[tid + i * 256];
        s += v.x + v.y + v.z + v.w;
        q += v.x*v.x + v.y*v.y + v.z*v.z + v.w*v.w;
    }
#pragma unroll
    for (int off = 32; off > 0; off >>= 1) {
        s += __shfl_down(s, off);
        q += __shfl_down(q, off);
    }
    __shared__ float ls[4], lq[4];
    int wid = tid >> 6;
    if ((tid & 63) == 0) { ls[wid] = s; lq[wid] = q; }
    __syncthreads();
    if (tid == 0) {
        part[pl]  = ls[0] + ls[1] + ls[2] + ls[3];
        partq[pl] = lq[0] + lq[1] + lq[2] + lq[3];
    }
}

// ---------- BN apply: o is block-uniform -> scalar stat reduce ----------
__global__ void __launch_bounds__(256)
bn_apply(float* __restrict__ out, const float* __restrict__ part,
         const float* __restrict__ partq,
         const float* __restrict__ gamma, const float* __restrict__ beta) {
    int o = blockIdx.x >> 1;              // 512 blocks, plane = blockIdx>>1 ... o = plane&31
    o &= 31;
    float S = 0.f, Q = 0.f;
#pragma unroll
    for (int b = 0; b < BATCH_; ++b) {
        S += part[b * 32 + o];
        Q += partq[b * 32 + o];
    }
    float mean = S * (1.f / (float)NPIX_);
    float var  = Q * (1.f / (float)NPIX_) - mean * mean;
    float rstd = rsqrtf(var + 1e-5f);
    float sc   = gamma[o] * rstd;
    float sh   = beta[o] - mean * sc;

    float4* f4 = reinterpret_cast<float4*>(out);
    int i4 = blockIdx.x * 512 + threadIdx.x;
#pragma unroll
    for (int half = 0; half < 2; ++half) {
        float4 v = f4[i4 + half * 256];
        v.x = v.x * sc + sh; v.y = v.y * sc + sh;
        v.z = v.z * sc + sh; v.w = v.w * sc + sh;
        f4[i4 + half * 256] = v;
    }
}

extern "C" void kernel_launch(void* const* d_in, const int* in_sizes, int n_in,
                              void* d_out, int out_size, void* d_ws, size_t ws_size,
                              hipStream_t stream) {
    const float* x     = (const float*)d_in[0];
    const float* W     = (const float*)d_in[1];
    const float* gamma = (const float*)d_in[2];
    const float* beta  = (const float*)d_in[3];
    float* out = (float*)d_out;
    unsigned short* Bpack = (unsigned short*)d_ws;
    float* part  = (float*)((char*)d_ws + PART_OFF);
    float* partq = (float*)((char*)d_ws + PARTQ_OFF);

    hipLaunchKernelGGL(wsum_kernel, dim3(144), dim3(256), 0, stream, W, Bpack);
    hipLaunchKernelGGL(main_kernel, dim3(512), dim3(256), 0, stream,
                       x, (const unsigned int*)Bpack, out);
    hipLaunchKernelGGL(bn_stats, dim3(256), dim3(256), 0, stream, out, part, partq);
    hipLaunchKernelGGL(bn_apply, dim3(512), dim3(256), 0, stream,
                       out, part, partq, gamma, beta);
}